// Round 11
// baseline (952.279 us; speedup 1.0000x reference)
//
#include <hip/hip_runtime.h>
#include <hip/hip_bf16.h>
#include <math.h>

constexpr int B = 64, N = 307, F = 64, T = 12, K = 3, C = 64, CT = 64;
constexpr float LN_EPS = 1e-5f;
constexpr int FT = F * T;  // 768

typedef float vf4 __attribute__((ext_vector_type(4)));
typedef short s16x8 __attribute__((ext_vector_type(8)));

__device__ __forceinline__ unsigned short f2bf(float f) {
    unsigned int u = __float_as_uint(f);
    unsigned int r = u + 0x7FFFu + ((u >> 16) & 1u);
    return (unsigned short)(r >> 16);
}

// ---------------- temporal attention ----------------

__global__ void k_lhs1_e(const float* __restrict__ x, const float* __restrict__ U1,
                         float* __restrict__ out) {
    int bb = blockIdx.x;
    int b = bb / 3;
    int e = (bb % 3) * 256 + threadIdx.x;  // e = f*T + t
    const float* xp = x + (size_t)b * N * FT + e;
    float s = 0.f;
    for (int n = 0; n < N; n++) s += xp[(size_t)n * FT] * U1[n];
    int f = e / T, t = e % T;
    out[((size_t)b * T + t) * F + f] = s;
}

__global__ void k_xdots(const float* __restrict__ x, const float* __restrict__ U3,
                        const float* __restrict__ W3, float* __restrict__ rhs_e,
                        float* __restrict__ xw3) {
    int idx = blockIdx.x * blockDim.x + threadIdx.x;
    if (idx >= B * N * T) return;
    int t = idx % T;
    size_t bn = idx / T;
    const float* xp = x + bn * F * T + t;
    float s1 = 0.f, s2 = 0.f;
    for (int f = 0; f < F; f++) {
        float v = xp[f * T];
        s1 += U3[f] * v;
        s2 += W3[f] * v;
    }
    rhs_e[idx] = s1;
    xw3[idx] = s2;
}

__global__ void k_lhs_e(const float* __restrict__ lhs1, const float* __restrict__ U2,
                        float* __restrict__ out) {
    int idx = blockIdx.x * blockDim.x + threadIdx.x;
    if (idx >= B * T * N) return;
    int n = idx % N;
    int bt = idx / N;
    const float* lp = lhs1 + (size_t)bt * F;
    float s = 0.f;
    for (int f = 0; f < F; f++) s += lp[f] * U2[f * N + n];
    out[idx] = s;
}

// prod/sigmoid/V_e/softmax fused per batch; also computes EW1[b,u]
__global__ void k_tatt(const float* __restrict__ lhs, const float* __restrict__ rhs,
                       const float* __restrict__ b_e, const float* __restrict__ V_e,
                       const float* __restrict__ W1, float* __restrict__ E,
                       float* __restrict__ EW1) {
    int b = blockIdx.x;
    int tid = threadIdx.x;  // 256
    __shared__ float ll[T][N + 1];
    __shared__ float rr_[T][N + 1];
    __shared__ float sig[T * T];
    __shared__ float Ev[T * T];
    __shared__ float mx[T], sm[T];
    for (int l = tid; l < T * N; l += 256) ll[l / N][l % N] = lhs[(size_t)b * T * N + l];
    for (int l = tid; l < N * T; l += 256) rr_[l % T][l / T] = rhs[(size_t)b * N * T + l];
    __syncthreads();
    if (tid < T * T) {
        int t = tid % T, u = tid / T;
        const vf4* lp4 = (const vf4*)&ll[u][0];
        const vf4* rp4 = (const vf4*)&rr_[t][0];
        float s = 0.f;
#pragma unroll 4
        for (int q = 0; q < 76; q++) {
            vf4 a = lp4[q], c = rp4[q];
            s += a[0] * c[0] + a[1] * c[1] + a[2] * c[2] + a[3] * c[3];
        }
        for (int n = 304; n < N; n++) s += ll[u][n] * rr_[t][n];
        s += b_e[u * T + t];
        sig[tid] = 1.f / (1.f + expf(-s));
    }
    __syncthreads();
    if (tid < T * T) {
        int t = tid % T, u = tid / T;
        float e = 0.f;
        for (int v = 0; v < T; v++) e += V_e[u * T + v] * sig[v * T + t];
        Ev[tid] = e;
    }
    __syncthreads();
    if (tid < T) {
        float m = -1e30f;
        for (int u = 0; u < T; u++) m = fmaxf(m, Ev[u * T + tid]);
        float s = 0.f;
        for (int u = 0; u < T; u++) s += expf(Ev[u * T + tid] - m);
        mx[tid] = m;
        sm[tid] = s;
    }
    __syncthreads();
    if (tid < T * T) {
        int t = tid % T;
        float val = expf(Ev[tid] - mx[t]) / sm[t];
        E[(size_t)b * T * T + tid] = val;
        sig[tid] = val;
    }
    __syncthreads();
    if (tid < T) {
        float s = 0.f;
        for (int t = 0; t < T; t++) s += sig[tid * T + t] * W1[t];
        EW1[(size_t)b * T + tid] = s;
    }
}

// ---------------- spatial attention ----------------

// v2: 4 rows per 256-thread block
__global__ void k_lhs_sf(const float* __restrict__ x, const float* __restrict__ EW1,
                         const float* __restrict__ W2, float* __restrict__ lhs_s) {
    int blk = blockIdx.x;       // 4912
    int sub = threadIdx.x >> 6; // 0..3
    int ft = threadIdx.x & 63;  // f
    size_t bn = (size_t)blk * 4 + sub;  // B*N = 19648 = 4912*4 exactly
    int b = (int)(bn / N);
    __shared__ float a[4][F];
    __shared__ float ew[4][T];
    if (ft < T) ew[sub][ft] = EW1[(size_t)b * T + ft];
    __syncthreads();
    const float* xp = x + bn * FT + ft * T;
    float s = 0.f;
#pragma unroll
    for (int tp = 0; tp < T; tp++) s += xp[tp] * ew[sub][tp];
    a[sub][ft] = s;
    __syncthreads();
    if (ft < T) {
        float s2 = 0.f;
#pragma unroll 8
        for (int f = 0; f < F; f++) s2 += a[sub][f] * W2[f * T + ft];
        lhs_s[bn * T + ft] = s2;
    }
}

__global__ void k_rhs_s2(const float* __restrict__ xw3, const float* __restrict__ E,
                         float* __restrict__ out) {
    int idx = blockIdx.x * blockDim.x + threadIdx.x;
    if (idx >= B * T * N) return;
    int m = idx % N;
    int t = (idx / N) % T;
    int b = idx / (N * T);
    const float* xp = xw3 + ((size_t)b * N + m) * T;
    const float* Ep = E + (size_t)b * T * T + t;
    float s = 0.f;
    for (int tp = 0; tp < T; tp++) s += xp[tp] * Ep[tp * T];
    out[idx] = s;
}

// merged prep: VsT, twT, ThT, chebT[k][j][i] = cheb[k][i][j]
constexpr int PREP_NN = N * N;
constexpr int PREP_TW = CT * C * 3;
constexpr int PREP_TH = K * F * C;
constexpr int PREP_TOT = PREP_NN + PREP_TW + PREP_TH;
constexpr int PREP_CHT = K * N * N;
constexpr int PREP_TOT2 = PREP_TOT + PREP_CHT;

__global__ void k_prep(const float* __restrict__ V, const float* __restrict__ tw,
                       const float* __restrict__ Th, const float* __restrict__ cheb,
                       float* __restrict__ VT, float* __restrict__ twT,
                       float* __restrict__ ThT, float* __restrict__ chebT) {
    int idx = blockIdx.x * blockDim.x + threadIdx.x;
    if (idx < PREP_NN) {
        int v = idx % N;
        int i = idx / N;
        VT[(size_t)v * N + i] = V[(size_t)i * N + v];
    } else if (idx < PREP_NN + PREP_TW) {
        int l = idx - PREP_NN;
        int dt = l % 3;
        int c = (l / 3) % C;
        int ct = l / (3 * C);
        twT[((size_t)dt * CT + ct) * C + c] = tw[l];
    } else if (idx < PREP_TOT) {
        int l = idx - PREP_NN - PREP_TW;
        int c = l % C;
        int f = (l / C) % F;
        int k = l / (C * F);
        ThT[((size_t)k * C + c) * F + f] = Th[l];
    } else if (idx < PREP_TOT2) {
        int l = idx - PREP_TOT;
        int i = l % N;
        int j = (l / N) % N;
        int k = l / (N * N);
        chebT[((size_t)k * N + j) * N + i] = cheb[((size_t)k * N + i) * N + j];
    }
}

// fused sigmoid + V_s projection (writes RAW pre-softmax S)
// v2: AT=8 rows per block -> VsT L2 re-reads halved (was the tail's biggest cost)
constexpr int AT = 8;
constexpr int NAB = (N + AT - 1) / AT;  // 39

__global__ void k_sigS(const float* __restrict__ lhs_s, const float* __restrict__ rhs_s,
                       const float* __restrict__ b_s, const float* __restrict__ VsT,
                       float* __restrict__ S) {
    int blk = blockIdx.x;
    int b = blk / NAB;
    int a0 = (blk % NAB) * AT;
    int tid = threadIdx.x;  // 256
    __shared__ float lrow[AT][T];
    __shared__ float sig4[AT][N];
    if (tid < AT * T) {
        int a = tid / T, t = tid % T;
        lrow[a][t] = (a0 + a < N) ? lhs_s[((size_t)b * N + a0 + a) * T + t] : 0.f;
    }
    __syncthreads();
    for (int v = tid; v < N; v += 256) {
        float rv[T];
        for (int t = 0; t < T; t++) rv[t] = rhs_s[((size_t)b * T + t) * N + v];
        for (int a = 0; a < AT; a++) {
            if (a0 + a >= N) break;
            float s = 0.f;
            for (int t = 0; t < T; t++) s += lrow[a][t] * rv[t];
            s += b_s[(size_t)(a0 + a) * N + v];
            sig4[a][v] = 1.f / (1.f + expf(-s));
        }
    }
    __syncthreads();
    for (int i = tid; i < N; i += 256) {
        float s[AT];
#pragma unroll
        for (int a = 0; a < AT; a++) s[a] = 0.f;
        for (int v = 0; v < N; v++) {
            float vt = VsT[(size_t)v * N + i];
#pragma unroll
            for (int a = 0; a < AT; a++) s[a] += sig4[a][v] * vt;
        }
#pragma unroll
        for (int a = 0; a < AT; a++)
            if (a0 + a < N) S[((size_t)b * N + a0 + a) * N + i] = s[a];
    }
}

// in-place softmax (fallback path)
__global__ void k_softmax_S(float* __restrict__ S) {
    int idx = blockIdx.x * blockDim.x + threadIdx.x;
    if (idx >= B * N) return;
    int b = idx / N;
    int i = idx % N;
    float* p = S + (size_t)b * N * N + i;
    float m = -1e30f;
    for (int a = 0; a < N; a++) m = fmaxf(m, p[(size_t)a * N]);
    float s = 0.f;
    for (int a = 0; a < N; a++) s += expf(p[(size_t)a * N] - m);
    float inv = 1.f / s;
    for (int a = 0; a < N; a++) p[(size_t)a * N] = expf(p[(size_t)a * N] - m) * inv;
}

// softmax over rows + transpose: ST[b][c][r] = softmaxed S[b][r][c]
__global__ void k_softT(const float* __restrict__ S, float* __restrict__ ST) {
    int b = blockIdx.x >> 1;
    int c0 = (blockIdx.x & 1) * 256;
    int tid = threadIdx.x;  // 256
    int c = c0 + tid;
    bool act = c < N;
    const float* p = S + (size_t)b * N * N + c;
    float m = -1e30f, s = 0.f;
    if (act) {
        for (int r = 0; r < N; r++) m = fmaxf(m, p[(size_t)r * N]);
        for (int r = 0; r < N; r++) s += expf(p[(size_t)r * N] - m);
    }
    float inv = act ? 1.f / s : 0.f;
    __shared__ float tile[32][257];
    float* STb = ST + (size_t)b * N * N;
    for (int r0 = 0; r0 < N; r0 += 32) {
        int rmax = min(32, N - r0);
        if (act)
            for (int rr = 0; rr < rmax; rr++)
                tile[rr][tid] = expf(p[(size_t)(r0 + rr) * N] - m) * inv;
        __syncthreads();
        for (int it = 0; it < 32; it++) {
            int cl = 8 * it + (tid >> 5);
            int cc = c0 + cl;
            int r = r0 + (tid & 31);
            if (cc < N && (tid & 31) < rmax) STb[(size_t)cc * N + r] = tile[tid & 31][cl];
        }
        __syncthreads();
    }
}

// ---------------- chebyshev graph conv + Theta + relu -> sg (in d_out) ----------------

constexpr int JT = 4;
constexpr int NJB = (N + JT - 1) / JT;  // 77
constexpr int GGRID = B * NJB;          // 4928 = 8*616
constexpr int IP = 320;                 // padded K dim (307 -> 320)

// xI: fragment-linear bf16 x. xI[((b*48+et)*10+ks)*64 + lane]*8 holds
// x[b][i=ks*32+(lane>>4)*8+r][e=et*16+(lane&15)] for r=0..7.
constexpr long XI_TOT = (long)B * 48 * 10 * 64;

__global__ void k_xI(const float* __restrict__ x, unsigned short* __restrict__ xI) {
    long idx = (long)blockIdx.x * 256 + threadIdx.x;
    if (idx >= XI_TOT) return;
    int lane = (int)(idx & 63);
    int ks = (int)((idx >> 6) % 10);
    int et = (int)((idx / 640) % 48);
    int b = (int)(idx / 30720);
    int col = lane & 15, kg = lane >> 4;
    int i0 = ks * 32 + kg * 8;
    int e = et * 16 + col;
    const float* xp = x + (size_t)b * N * FT + e;
    s16x8 out;
#pragma unroll
    for (int r = 0; r < 8; r++) {
        int i = i0 + r;
        out[r] = (i < N) ? (short)f2bf(xp[(size_t)i * FT]) : (short)0;
    }
    *(s16x8*)(xI + (size_t)idx * 8) = out;
}

// WqT[b][jb][q=k*4+jj][i320] bf16 = cheb[k][i][j]*S[b][i][j], j = jb*4+jj
__global__ void k_Wq16(const float* __restrict__ chebT, const float* __restrict__ ST,
                       unsigned short* __restrict__ Wq) {
    long idx = (long)blockIdx.x * 256 + threadIdx.x;
    long tot = (long)B * NJB * 12 * IP;
    if (idx >= tot) return;
    int i = (int)(idx % IP);
    int q = (int)((idx / IP) % 12);
    int jb = (int)((idx / (12L * IP)) % NJB);
    int b = (int)(idx / (12L * IP * NJB));
    int k = q >> 2, jj = q & 3, j = jb * 4 + jj;
    float w = 0.f;
    if (i < N && j < N)
        w = chebT[((size_t)k * N + j) * N + i] * ST[((size_t)b * N + j) * N + i];
    Wq[idx] = f2bf(w);
}

// MFMA stage-1 v5: round-8 structure with ks-granular double-buffer pipeline:
// issue all 12 x-frags + w for ks+1 while executing ks's 12 MFMAs (issue->use
// gap ~110cy vs 53cy at half-step granularity -> L2-latency stall halved).
// launch_bounds(256,2): VGPR cap 256 -> NO spill possible (r9 lesson: (512,6)'s
// 85-cap spilled 620MB). Expected VGPR ~150-165; tripwire = WRITE_SIZE >> 73MB.
__global__ __launch_bounds__(256, 2) void k_gcnz_m(const unsigned short* __restrict__ xI,
                                                   const unsigned short* __restrict__ WqT,
                                                   const float* __restrict__ ThT,
                                                   float* __restrict__ sg) {
    int blk0 = blockIdx.x;
    int blk = (blk0 & 7) * (GGRID / 8) + (blk0 >> 3);  // XCD swizzle (bijective: 4928=8*616)
    int b = blk / NJB;
    int jb = blk % NJB;
    int j0 = jb * JT;
    int tid = threadIdx.x;  // 256
    int w = tid >> 6;
    int lane = tid & 63;
    int col = lane & 15;  // A-row (q) / B-col (e within 16-tile)
    int kg = lane >> 4;

    __shared__ float zlf[3 * 3080];  // 3 k-planes of 3072 + 8 pad

    vf4 acc[12];
#pragma unroll
    for (int mt = 0; mt < 12; mt++) acc[mt] = (vf4){0.f, 0.f, 0.f, 0.f};

    const unsigned short* xb =
        xI + ((size_t)(b * 48 + w * 12) * 10) * 512 + (size_t)lane * 8;
    const unsigned short* wb =
        WqT + ((size_t)(b * NJB + jb) * 12 + (col < 12 ? col : 11)) * IP + kg * 8;

    s16x8 xa[12], xc[12], wa, wc;
    auto ldg = [&](s16x8* d, s16x8& wreg, int ks) {
        wreg = *(const s16x8*)(wb + ks * 32);
#pragma unroll
        for (int m = 0; m < 12; m++)
            d[m] = *(const s16x8*)(xb + (size_t)(m * 10 + ks) * 512);
    };
    auto mma = [&](const s16x8* d, s16x8 wreg) {
#pragma unroll
        for (int m = 0; m < 12; m++)
            acc[m] = __builtin_amdgcn_mfma_f32_16x16x32_bf16(wreg, d[m], acc[m], 0, 0, 0);
    };

    ldg(xa, wa, 0);
#pragma unroll
    for (int ks2 = 0; ks2 < 5; ks2++) {
        ldg(xc, wc, 2 * ks2 + 1);   // in flight across mma(xa)
        mma(xa, wa);
        if (ks2 < 4) ldg(xa, wa, 2 * ks2 + 2);  // in flight across mma(xc)
        mma(xc, wc);
    }

    if (kg < 3) {
        // acc[mt]: q = kg*4 + 0..3 for e = w*192 + mt*16 + col -> one b128 per mt
#pragma unroll
        for (int mt = 0; mt < 12; mt++) {
            int e = w * 192 + mt * 16 + col;  // = f*T + t
            *(vf4*)(zlf + kg * 3080 + e * 4) = acc[mt];
        }
    }
    __syncthreads();

    // Theta contraction, c-blocked (192 active threads)
    if (tid < 192) {
        int t = tid % T;
        int c0 = (tid / T) * 4;
        float s[4][4];
#pragma unroll
        for (int cc = 0; cc < 4; cc++)
#pragma unroll
            for (int jj = 0; jj < 4; jj++) s[cc][jj] = 0.f;

#pragma unroll
        for (int k = 0; k < K; k++) {
            const vf4* zpk = (const vf4*)(zlf + k * 3080 + t * 4);
            const vf4* tp0 = (const vf4*)(ThT + ((size_t)k * C + c0 + 0) * F);
            const vf4* tp1 = (const vf4*)(ThT + ((size_t)k * C + c0 + 1) * F);
            const vf4* tp2 = (const vf4*)(ThT + ((size_t)k * C + c0 + 2) * F);
            const vf4* tp3 = (const vf4*)(ThT + ((size_t)k * C + c0 + 3) * F);
#pragma unroll 4
            for (int fq = 0; fq < F / 4; fq++) {
                vf4 z0 = zpk[(4 * fq + 0) * 12];
                vf4 z1 = zpk[(4 * fq + 1) * 12];
                vf4 z2 = zpk[(4 * fq + 2) * 12];
                vf4 z3 = zpk[(4 * fq + 3) * 12];
                vf4 th[4];
                th[0] = tp0[fq];
                th[1] = tp1[fq];
                th[2] = tp2[fq];
                th[3] = tp3[fq];
#pragma unroll
                for (int cc = 0; cc < 4; cc++) {
#pragma unroll
                    for (int jj = 0; jj < 4; jj++)
                        s[cc][jj] += th[cc][0] * z0[jj] + th[cc][1] * z1[jj] +
                                     th[cc][2] * z2[jj] + th[cc][3] * z3[jj];
                }
            }
        }
#pragma unroll
        for (int jj = 0; jj < 4; jj++) {
            int j = j0 + jj;
            if (j < N) {
                float* op = sg + ((size_t)b * N + j) * FT + (size_t)c0 * T + t;
                op[0 * T] = fmaxf(s[0][jj], 0.f);
                op[1 * T] = fmaxf(s[1][jj], 0.f);
                op[2 * T] = fmaxf(s[2][jj], 0.f);
                op[3 * T] = fmaxf(s[3][jj], 0.f);
            }
        }
    }
}

// ---------------- fallback fp32 path (round-6, known-good) ----------------

__global__ void k_Wp(const float* __restrict__ cheb, const float* __restrict__ S,
                     float* __restrict__ Wp) {
    long idx = (long)blockIdx.x * 256 + threadIdx.x;
    long tot = (long)B * NJB * N * 12;
    if (idx >= tot) return;
    int q = (int)(idx % 12);
    int i = (int)((idx / 12) % N);
    int jb = (int)((idx / (12L * N)) % NJB);
    int b = (int)(idx / (12L * N * NJB));
    int k = q >> 2, jj = q & 3;
    int j = jb * 4 + jj;
    float w = 0.f;
    if (j < N) w = cheb[((size_t)k * N + i) * N + j] * S[((size_t)b * N + i) * N + j];
    Wp[idx] = w;
}

__global__ __launch_bounds__(256, 4) void k_gcnz_p(const float* __restrict__ x,
                                                   const float* __restrict__ Wp,
                                                   const float* __restrict__ ThT,
                                                   float* __restrict__ sg) {
    int blk0 = blockIdx.x;
    int blk = (blk0 & 7) * (GGRID / 8) + (blk0 >> 3);
    int b = blk / NJB;
    int jb = blk % NJB;
    int j0 = jb * JT;
    int tid = threadIdx.x;

    __shared__ float zl[K][F][T][JT];

    float acc[K * JT][3];
#pragma unroll
    for (int m = 0; m < K * JT; m++)
#pragma unroll
        for (int r = 0; r < 3; r++) acc[m][r] = 0.f;

    const float* xp = x + (size_t)b * N * FT + 3 * tid;
    const float* wb = Wp + ((size_t)b * NJB + jb) * N * 12;

    float w0[12], w1[12], w2[12];
    float x0[3], x1[3], x2[3];

    auto LD = [&](float* wreg, float* xreg, int i) {
        const vf4* p = (const vf4*)(wb + (size_t)i * 12);
        vf4 a = p[0], b4 = p[1], c4 = p[2];
#pragma unroll
        for (int q = 0; q < 4; q++) {
            wreg[q] = a[q];
            wreg[4 + q] = b4[q];
            wreg[8 + q] = c4[q];
        }
        const float* xq = xp + (size_t)i * FT;
        xreg[0] = xq[0];
        xreg[1] = xq[1];
        xreg[2] = xq[2];
    };
    auto FMA = [&](const float* wreg, const float* xreg) {
#pragma unroll
        for (int m = 0; m < K * JT; m++) {
            acc[m][0] += wreg[m] * xreg[0];
            acc[m][1] += wreg[m] * xreg[1];
            acc[m][2] += wreg[m] * xreg[2];
        }
    };

    LD(w0, x0, 0);
    LD(w1, x1, 1);
    LD(w2, x2, 2);
    int i = 0;
    for (; i + 5 < N; i += 3) {
        float a0[12], a1[12], a2[12], y0[3], y1[3], y2[3];
        LD(a0, y0, i + 3);
        LD(a1, y1, i + 4);
        LD(a2, y2, i + 5);
        FMA(w0, x0);
        FMA(w1, x1);
        FMA(w2, x2);
#pragma unroll
        for (int m = 0; m < 12; m++) {
            w0[m] = a0[m];
            w1[m] = a1[m];
            w2[m] = a2[m];
        }
#pragma unroll
        for (int r = 0; r < 3; r++) {
            x0[r] = y0[r];
            x1[r] = y1[r];
            x2[r] = y2[r];
        }
    }
    FMA(w0, x0);
    FMA(w1, x1);
    FMA(w2, x2);
    for (i += 3; i < N; i++) {
        LD(w0, x0, i);
        FMA(w0, x0);
    }

#pragma unroll
    for (int r = 0; r < 3; r++) {
        int e = 3 * tid + r;
        int f = e / T, t = e % T;
#pragma unroll
        for (int m = 0; m < K * JT; m++) zl[m >> 2][f][t][m & 3] = acc[m][r];
    }
    __syncthreads();

    if (tid < 192) {
        int t = tid % T;
        int c0 = (tid / T) * 4;
        float s[4][4];
#pragma unroll
        for (int cc = 0; cc < 4; cc++)
#pragma unroll
            for (int jj = 0; jj < 4; jj++) s[cc][jj] = 0.f;

#pragma unroll
        for (int k = 0; k < K; k++) {
            const vf4* zpk = (const vf4*)&zl[k][0][t][0];
            const vf4* tp0 = (const vf4*)(ThT + ((size_t)k * C + c0 + 0) * F);
            const vf4* tp1 = (const vf4*)(ThT + ((size_t)k * C + c0 + 1) * F);
            const vf4* tp2 = (const vf4*)(ThT + ((size_t)k * C + c0 + 2) * F);
            const vf4* tp3 = (const vf4*)(ThT + ((size_t)k * C + c0 + 3) * F);
#pragma unroll 4
            for (int fq = 0; fq < F / 4; fq++) {
                vf4 z0 = zpk[(4 * fq + 0) * 12];
                vf4 z1 = zpk[(4 * fq + 1) * 12];
                vf4 z2 = zpk[(4 * fq + 2) * 12];
                vf4 z3 = zpk[(4 * fq + 3) * 12];
                vf4 th[4];
                th[0] = tp0[fq];
                th[1] = tp1[fq];
                th[2] = tp2[fq];
                th[3] = tp3[fq];
#pragma unroll
                for (int cc = 0; cc < 4; cc++) {
#pragma unroll
                    for (int jj = 0; jj < 4; jj++)
                        s[cc][jj] += th[cc][0] * z0[jj] + th[cc][1] * z1[jj] +
                                     th[cc][2] * z2[jj] + th[cc][3] * z3[jj];
                }
            }
        }
#pragma unroll
        for (int jj = 0; jj < 4; jj++) {
            int j = j0 + jj;
            if (j < N) {
                float* op = sg + ((size_t)b * N + j) * FT + (size_t)c0 * T + t;
                op[0 * T] = fmaxf(s[0][jj], 0.f);
                op[1 * T] = fmaxf(s[1][jj], 0.f);
                op[2 * T] = fmaxf(s[2][jj], 0.f);
                op[3 * T] = fmaxf(s[3][jj], 0.f);
            }
        }
    }
}

// ---------------- tconv + rconv + relu + LayerNorm (in-place on d_out) ----------------

constexpr int RB = 4;
constexpr int PF = 68;

__global__ void k_rest(const float* __restrict__ x, const float* __restrict__ twT,
                       const float* __restrict__ tb, const float* __restrict__ rw,
                       const float* __restrict__ rb, const float* __restrict__ gamma,
                       const float* __restrict__ beta, float* __restrict__ io) {
    int blk = blockIdx.x;
    size_t bn0 = (size_t)blk * RB;
    int tid = threadIdx.x;  // 192

    __shared__ float xt[RB][T][PF];
    __shared__ float sgt[RB][T + 2][PF];
    __shared__ float red0[RB][T][17];
    __shared__ float red1[RB][T][17];
    __shared__ float mus[RB][T], rstds[RB][T];

    for (int l = tid; l < RB * PF; l += 192) {
        int rr = l / PF, c = l % PF;
        sgt[rr][0][c] = 0.f;
        sgt[rr][T + 1][c] = 0.f;
    }
    for (int l = tid; l < RB * FT; l += 192) {
        int rr = l / FT, rem = l % FT;
        int f = rem / T, t = rem % T;
        xt[rr][t][f] = x[(bn0 + rr) * FT + rem];
        sgt[rr][t + 1][f] = io[(bn0 + rr) * FT + rem];
    }
    __syncthreads();

    int t = tid % T;
    int cg = tid / T;
    int ct0 = cg * 4;

    float acc[RB][4];
#pragma unroll
    for (int rr = 0; rr < RB; rr++)
#pragma unroll
        for (int q = 0; q < 4; q++) acc[rr][q] = rb[ct0 + q] + tb[ct0 + q];

    {
        const vf4* w0 = (const vf4*)(rw + (size_t)(ct0 + 0) * F);
        const vf4* w1 = (const vf4*)(rw + (size_t)(ct0 + 1) * F);
        const vf4* w2 = (const vf4*)(rw + (size_t)(ct0 + 2) * F);
        const vf4* w3 = (const vf4*)(rw + (size_t)(ct0 + 3) * F);
#pragma unroll 4
        for (int fq = 0; fq < F / 4; fq++) {
            vf4 a = w0[fq], b4 = w1[fq], c4 = w2[fq], d4 = w3[fq];
#pragma unroll
            for (int rr = 0; rr < RB; rr++) {
                vf4 v = *(const vf4*)(&xt[rr][t][fq * 4]);
                acc[rr][0] += a[0] * v[0] + a[1] * v[1] + a[2] * v[2] + a[3] * v[3];
                acc[rr][1] += b4[0] * v[0] + b4[1] * v[1] + b4[2] * v[2] + b4[3] * v[3];
                acc[rr][2] += c4[0] * v[0] + c4[1] * v[1] + c4[2] * v[2] + c4[3] * v[3];
                acc[rr][3] += d4[0] * v[0] + d4[1] * v[1] + d4[2] * v[2] + d4[3] * v[3];
            }
        }
    }
#pragma unroll
    for (int dt = 0; dt < 3; dt++) {
        const vf4* w0 = (const vf4*)(twT + ((size_t)dt * CT + ct0 + 0) * C);
        const vf4* w1 = (const vf4*)(twT + ((size_t)dt * CT + ct0 + 1) * C);
        const vf4* w2 = (const vf4*)(twT + ((size_t)dt * CT + ct0 + 2) * C);
        const vf4* w3 = (const vf4*)(twT + ((size_t)dt * CT + ct0 + 3) * C);
#pragma unroll 4
        for (int fq = 0; fq < C / 4; fq++) {
            vf4 a = w0[fq], b4 = w1[fq], c4 = w2[fq], d4 = w3[fq];
#pragma unroll
            for (int rr = 0; rr < RB; rr++) {
                vf4 v = *(const vf4*)(&sgt[rr][t + dt][fq * 4]);
                acc[rr][0] += a[0] * v[0] + a[1] * v[1] + a[2] * v[2] + a[3] * v[3];
                acc[rr][1] += b4[0] * v[0] + b4[1] * v[1] + b4[2] * v[2] + b4[3] * v[3];
                acc[rr][2] += c4[0] * v[0] + c4[1] * v[1] + c4[2] * v[2] + c4[3] * v[3];
                acc[rr][3] += d4[0] * v[0] + d4[1] * v[1] + d4[2] * v[2] + d4[3] * v[3];
            }
        }
    }

#pragma unroll
    for (int rr = 0; rr < RB; rr++) {
        float ps = 0.f;
#pragma unroll
        for (int q = 0; q < 4; q++) {
            float h = fmaxf(acc[rr][q], 0.f);
            acc[rr][q] = h;
            ps += h;
        }
        red0[rr][t][cg] = ps;
    }
    __syncthreads();
    if (tid < RB * T) {
        int rr = tid / T, tt = tid % T;
        float m = 0.f;
#pragma unroll 4
        for (int g = 0; g < 16; g++) m += red0[rr][tt][g];
        mus[rr][tt] = m * (1.f / CT);
    }
    __syncthreads();
#pragma unroll
    for (int rr = 0; rr < RB; rr++) {
        float m = mus[rr][t];
        float pv = 0.f;
#pragma unroll
        for (int q = 0; q < 4; q++) {
            float d = acc[rr][q] - m;
            pv += d * d;
        }
        red1[rr][t][cg] = pv;
    }
    __syncthreads();
    if (tid < RB * T) {
        int rr = tid / T, tt = tid % T;
        float v = 0.f;
#pragma unroll 4
        for (int g = 0; g < 16; g++) v += red1[rr][tt][g];
        rstds[rr][tt] = rsqrtf(v * (1.f / CT) + LN_EPS);
    }
    __syncthreads();
#pragma unroll
    for (int rr = 0; rr < RB; rr++) {
        float m = mus[rr][t], rs = rstds[rr][t];
        float* iop = io + (bn0 + rr) * FT;
#pragma unroll
        for (int q = 0; q < 4; q++) {
            int ct = ct0 + q;
            iop[ct * T + t] = (acc[rr][q] - m) * rs * gamma[ct] + beta[ct];
        }
    }
}

// ---------------- launch ----------------

extern "C" void kernel_launch(void* const* d_in, const int* in_sizes, int n_in,
                              void* d_out, int out_size, void* d_ws, size_t ws_size,
                              hipStream_t stream) {
    const float* x     = (const float*)d_in[0];
    const float* W1    = (const float*)d_in[1];
    const float* W2    = (const float*)d_in[2];
    const float* W3    = (const float*)d_in[3];
    const float* b_s   = (const float*)d_in[4];
    const float* V_s   = (const float*)d_in[5];
    const float* U1    = (const float*)d_in[6];
    const float* U2    = (const float*)d_in[7];
    const float* U3    = (const float*)d_in[8];
    const float* b_e   = (const float*)d_in[9];
    const float* V_e   = (const float*)d_in[10];
    const float* cheb  = (const float*)d_in[11];
    const float* Theta = (const float*)d_in[12];
    const float* tw    = (const float*)d_in[13];
    const float* tb    = (const float*)d_in[14];
    const float* rw    = (const float*)d_in[15];
    const float* rb    = (const float*)d_in[16];
    const float* gam   = (const float*)d_in[17];
    const float* bet   = (const float*)d_in[18];
    float* out = (float*)d_out;

    float* ws = (float*)d_ws;
    size_t off = 0;
    auto alloc = [&](size_t n) { float* p = ws + off; off += n; return p; };
    // persistent
    float* VsT = alloc((size_t)N * N);
    float* twT = alloc((size_t)CT * C * 3);
    float* ThT = alloc((size_t)K * F * C);
    size_t base_end = off;
    // attention transients (dead before k_Wq16)
    float* lhs1_e = alloc((size_t)B * T * F);
    float* lhs_e  = alloc((size_t)B * T * N);
    float* rhs_e  = alloc((size_t)B * N * T);
    float* Ebuf   = alloc((size_t)B * T * T);
    float* EW1    = alloc((size_t)B * T);
    float* xw3    = alloc((size_t)B * N * T);
    float* lhs_s  = alloc((size_t)B * N * T);
    float* rhs_s  = alloc((size_t)B * T * N);
    float* Sb     = alloc((size_t)B * N * N);
    size_t poolA_end = off;

    // MFMA-path buffers: WqT overlays transients (written after they're dead)
    size_t wq_fl = (size_t)B * NJB * 12 * IP / 2;  // ushorts/2
    unsigned short* WqT = (unsigned short*)(ws + base_end);
    size_t off2 = base_end + wq_fl;
    if (off2 < poolA_end) off2 = poolA_end;
    float* chebT = ws + off2; off2 += (size_t)K * N * N;
    float* SbT = ws + off2; off2 += (size_t)B * N * N;
    unsigned short* xI = (unsigned short*)(ws + off2);
    off2 += (size_t)XI_TOT * 8 / 2;
    bool useM = ws_size >= off2 * sizeof(float);

    // fallback fp32 Wp (round-6 layout)
    size_t wp_off = (poolA_end + 3) & ~(size_t)3;
    float* Wp = ws + wp_off;
    bool useWp = !useM && ws_size >= (wp_off + (size_t)B * NJB * N * 12) * sizeof(float);

    auto g = [](long n) { return dim3((unsigned)((n + 255) / 256)); };

    // prep (chebT section only needed when useM)
    k_prep<<<g(useM ? (long)PREP_TOT2 : (long)PREP_TOT), 256, 0, stream>>>(
        V_s, tw, Theta, cheb, VsT, twT, ThT, chebT);
    if (useM) k_xI<<<g(XI_TOT), 256, 0, stream>>>(x, xI);

    // temporal attention
    k_lhs1_e<<<dim3(B * 3), 256, 0, stream>>>(x, U1, lhs1_e);
    k_xdots<<<g((long)B * N * T), 256, 0, stream>>>(x, U3, W3, rhs_e, xw3);
    k_lhs_e<<<g((long)B * T * N), 256, 0, stream>>>(lhs1_e, U2, lhs_e);
    k_tatt<<<B, 256, 0, stream>>>(lhs_e, rhs_e, b_e, V_e, W1, Ebuf, EW1);

    // spatial attention
    k_lhs_sf<<<dim3((B * N) / 4), 256, 0, stream>>>(x, EW1, W2, lhs_s);
    k_rhs_s2<<<g((long)B * T * N), 256, 0, stream>>>(xw3, Ebuf, rhs_s);
    k_sigS<<<B * NAB, 256, 0, stream>>>(lhs_s, rhs_s, b_s, VsT, Sb);

    // graph conv + Theta + relu -> sg staged in d_out
    if (useM) {
        k_softT<<<dim3(B * 2), 256, 0, stream>>>(Sb, SbT);
        k_Wq16<<<g((long)B * NJB * 12 * IP), 256, 0, stream>>>(chebT, SbT, WqT);
        k_gcnz_m<<<GGRID, 256, 0, stream>>>(xI, WqT, ThT, out);
    } else if (useWp) {
        k_softmax_S<<<g((long)B * N), 256, 0, stream>>>(Sb);
        k_Wp<<<g((long)B * NJB * N * 12), 256, 0, stream>>>(cheb, Sb, Wp);
        k_gcnz_p<<<GGRID, 256, 0, stream>>>(x, Wp, ThT, out);
    }

    // tconv + rconv + relu + LN, in-place on d_out
    k_rest<<<(B * N) / RB, 192, 0, stream>>>(x, twT, tb, rw, rb, gam, bet, out);
}

// Round 12
// 899.116 us; speedup vs baseline: 1.0591x; 1.0591x over previous
//
#include <hip/hip_runtime.h>
#include <hip/hip_bf16.h>
#include <math.h>

constexpr int B = 64, N = 307, F = 64, T = 12, K = 3, C = 64, CT = 64;
constexpr float LN_EPS = 1e-5f;
constexpr int FT = F * T;  // 768

typedef float vf4 __attribute__((ext_vector_type(4)));
typedef short s16x8 __attribute__((ext_vector_type(8)));

__device__ __forceinline__ unsigned short f2bf(float f) {
    unsigned int u = __float_as_uint(f);
    unsigned int r = u + 0x7FFFu + ((u >> 16) & 1u);
    return (unsigned short)(r >> 16);
}

// ---------------- temporal attention ----------------

__global__ void k_lhs1_e(const float* __restrict__ x, const float* __restrict__ U1,
                         float* __restrict__ out) {
    int bb = blockIdx.x;
    int b = bb / 3;
    int e = (bb % 3) * 256 + threadIdx.x;  // e = f*T + t
    const float* xp = x + (size_t)b * N * FT + e;
    float s = 0.f;
    for (int n = 0; n < N; n++) s += xp[(size_t)n * FT] * U1[n];
    int f = e / T, t = e % T;
    out[((size_t)b * T + t) * F + f] = s;
}

__global__ void k_xdots(const float* __restrict__ x, const float* __restrict__ U3,
                        const float* __restrict__ W3, float* __restrict__ rhs_e,
                        float* __restrict__ xw3) {
    int idx = blockIdx.x * blockDim.x + threadIdx.x;
    if (idx >= B * N * T) return;
    int t = idx % T;
    size_t bn = idx / T;
    const float* xp = x + bn * F * T + t;
    float s1 = 0.f, s2 = 0.f;
    for (int f = 0; f < F; f++) {
        float v = xp[f * T];
        s1 += U3[f] * v;
        s2 += W3[f] * v;
    }
    rhs_e[idx] = s1;
    xw3[idx] = s2;
}

__global__ void k_lhs_e(const float* __restrict__ lhs1, const float* __restrict__ U2,
                        float* __restrict__ out) {
    int idx = blockIdx.x * blockDim.x + threadIdx.x;
    if (idx >= B * T * N) return;
    int n = idx % N;
    int bt = idx / N;
    const float* lp = lhs1 + (size_t)bt * F;
    float s = 0.f;
    for (int f = 0; f < F; f++) s += lp[f] * U2[f * N + n];
    out[idx] = s;
}

// prod/sigmoid/V_e/softmax fused per batch; also computes EW1[b,u]
__global__ void k_tatt(const float* __restrict__ lhs, const float* __restrict__ rhs,
                       const float* __restrict__ b_e, const float* __restrict__ V_e,
                       const float* __restrict__ W1, float* __restrict__ E,
                       float* __restrict__ EW1) {
    int b = blockIdx.x;
    int tid = threadIdx.x;  // 256
    __shared__ float ll[T][N + 1];
    __shared__ float rr_[T][N + 1];
    __shared__ float sig[T * T];
    __shared__ float Ev[T * T];
    __shared__ float mx[T], sm[T];
    for (int l = tid; l < T * N; l += 256) ll[l / N][l % N] = lhs[(size_t)b * T * N + l];
    for (int l = tid; l < N * T; l += 256) rr_[l % T][l / T] = rhs[(size_t)b * N * T + l];
    __syncthreads();
    if (tid < T * T) {
        int t = tid % T, u = tid / T;
        const vf4* lp4 = (const vf4*)&ll[u][0];
        const vf4* rp4 = (const vf4*)&rr_[t][0];
        float s = 0.f;
#pragma unroll 4
        for (int q = 0; q < 76; q++) {
            vf4 a = lp4[q], c = rp4[q];
            s += a[0] * c[0] + a[1] * c[1] + a[2] * c[2] + a[3] * c[3];
        }
        for (int n = 304; n < N; n++) s += ll[u][n] * rr_[t][n];
        s += b_e[u * T + t];
        sig[tid] = 1.f / (1.f + expf(-s));
    }
    __syncthreads();
    if (tid < T * T) {
        int t = tid % T, u = tid / T;
        float e = 0.f;
        for (int v = 0; v < T; v++) e += V_e[u * T + v] * sig[v * T + t];
        Ev[tid] = e;
    }
    __syncthreads();
    if (tid < T) {
        float m = -1e30f;
        for (int u = 0; u < T; u++) m = fmaxf(m, Ev[u * T + tid]);
        float s = 0.f;
        for (int u = 0; u < T; u++) s += expf(Ev[u * T + tid] - m);
        mx[tid] = m;
        sm[tid] = s;
    }
    __syncthreads();
    if (tid < T * T) {
        int t = tid % T;
        float val = expf(Ev[tid] - mx[t]) / sm[t];
        E[(size_t)b * T * T + tid] = val;
        sig[tid] = val;
    }
    __syncthreads();
    if (tid < T) {
        float s = 0.f;
        for (int t = 0; t < T; t++) s += sig[tid * T + t] * W1[t];
        EW1[(size_t)b * T + tid] = s;
    }
}

// ---------------- spatial attention ----------------

// v2: 4 rows per 256-thread block
__global__ void k_lhs_sf(const float* __restrict__ x, const float* __restrict__ EW1,
                         const float* __restrict__ W2, float* __restrict__ lhs_s) {
    int blk = blockIdx.x;       // 4912
    int sub = threadIdx.x >> 6; // 0..3
    int ft = threadIdx.x & 63;  // f
    size_t bn = (size_t)blk * 4 + sub;  // B*N = 19648 = 4912*4 exactly
    int b = (int)(bn / N);
    __shared__ float a[4][F];
    __shared__ float ew[4][T];
    if (ft < T) ew[sub][ft] = EW1[(size_t)b * T + ft];
    __syncthreads();
    const float* xp = x + bn * FT + ft * T;
    float s = 0.f;
#pragma unroll
    for (int tp = 0; tp < T; tp++) s += xp[tp] * ew[sub][tp];
    a[sub][ft] = s;
    __syncthreads();
    if (ft < T) {
        float s2 = 0.f;
#pragma unroll 8
        for (int f = 0; f < F; f++) s2 += a[sub][f] * W2[f * T + ft];
        lhs_s[bn * T + ft] = s2;
    }
}

__global__ void k_rhs_s2(const float* __restrict__ xw3, const float* __restrict__ E,
                         float* __restrict__ out) {
    int idx = blockIdx.x * blockDim.x + threadIdx.x;
    if (idx >= B * T * N) return;
    int m = idx % N;
    int t = (idx / N) % T;
    int b = idx / (N * T);
    const float* xp = xw3 + ((size_t)b * N + m) * T;
    const float* Ep = E + (size_t)b * T * T + t;
    float s = 0.f;
    for (int tp = 0; tp < T; tp++) s += xp[tp] * Ep[tp * T];
    out[idx] = s;
}

// merged prep: VsT, twT, ThT, chebT[k][j][i] = cheb[k][i][j]
constexpr int PREP_NN = N * N;
constexpr int PREP_TW = CT * C * 3;
constexpr int PREP_TH = K * F * C;
constexpr int PREP_TOT = PREP_NN + PREP_TW + PREP_TH;
constexpr int PREP_CHT = K * N * N;
constexpr int PREP_TOT2 = PREP_TOT + PREP_CHT;

__global__ void k_prep(const float* __restrict__ V, const float* __restrict__ tw,
                       const float* __restrict__ Th, const float* __restrict__ cheb,
                       float* __restrict__ VT, float* __restrict__ twT,
                       float* __restrict__ ThT, float* __restrict__ chebT) {
    int idx = blockIdx.x * blockDim.x + threadIdx.x;
    if (idx < PREP_NN) {
        int v = idx % N;
        int i = idx / N;
        VT[(size_t)v * N + i] = V[(size_t)i * N + v];
    } else if (idx < PREP_NN + PREP_TW) {
        int l = idx - PREP_NN;
        int dt = l % 3;
        int c = (l / 3) % C;
        int ct = l / (3 * C);
        twT[((size_t)dt * CT + ct) * C + c] = tw[l];
    } else if (idx < PREP_TOT) {
        int l = idx - PREP_NN - PREP_TW;
        int c = l % C;
        int f = (l / C) % F;
        int k = l / (C * F);
        ThT[((size_t)k * C + c) * F + f] = Th[l];
    } else if (idx < PREP_TOT2) {
        int l = idx - PREP_TOT;
        int i = l % N;
        int j = (l / N) % N;
        int k = l / (N * N);
        chebT[((size_t)k * N + j) * N + i] = cheb[((size_t)k * N + i) * N + j];
    }
}

// fused sigmoid + V_s projection (writes RAW pre-softmax S), AT=4 (round-10 proven;
// AT=8 regressed ~30us in r11)
constexpr int AT = 4;
constexpr int NAB = (N + AT - 1) / AT;  // 77

__global__ void k_sigS(const float* __restrict__ lhs_s, const float* __restrict__ rhs_s,
                       const float* __restrict__ b_s, const float* __restrict__ VsT,
                       float* __restrict__ S) {
    int blk = blockIdx.x;
    int b = blk / NAB;
    int a0 = (blk % NAB) * AT;
    int tid = threadIdx.x;  // 256
    __shared__ float lrow[AT][T];
    __shared__ float sig4[AT][N];
    if (tid < AT * T) {
        int a = tid / T, t = tid % T;
        lrow[a][t] = (a0 + a < N) ? lhs_s[((size_t)b * N + a0 + a) * T + t] : 0.f;
    }
    __syncthreads();
    for (int v = tid; v < N; v += 256) {
        float rv[T];
        for (int t = 0; t < T; t++) rv[t] = rhs_s[((size_t)b * T + t) * N + v];
        for (int a = 0; a < AT; a++) {
            if (a0 + a >= N) break;
            float s = 0.f;
            for (int t = 0; t < T; t++) s += lrow[a][t] * rv[t];
            s += b_s[(size_t)(a0 + a) * N + v];
            sig4[a][v] = 1.f / (1.f + expf(-s));
        }
    }
    __syncthreads();
    for (int i = tid; i < N; i += 256) {
        float s[AT] = {0.f, 0.f, 0.f, 0.f};
        for (int v = 0; v < N; v++) {
            float vt = VsT[(size_t)v * N + i];
            for (int a = 0; a < AT; a++) s[a] += sig4[a][v] * vt;
        }
        for (int a = 0; a < AT; a++)
            if (a0 + a < N) S[((size_t)b * N + a0 + a) * N + i] = s[a];
    }
}

// in-place softmax (fallback path)
__global__ void k_softmax_S(float* __restrict__ S) {
    int idx = blockIdx.x * blockDim.x + threadIdx.x;
    if (idx >= B * N) return;
    int b = idx / N;
    int i = idx % N;
    float* p = S + (size_t)b * N * N + i;
    float m = -1e30f;
    for (int a = 0; a < N; a++) m = fmaxf(m, p[(size_t)a * N]);
    float s = 0.f;
    for (int a = 0; a < N; a++) s += expf(p[(size_t)a * N] - m);
    float inv = 1.f / s;
    for (int a = 0; a < N; a++) p[(size_t)a * N] = expf(p[(size_t)a * N] - m) * inv;
}

// softmax over rows + transpose: ST[b][c][r] = softmaxed S[b][r][c]
__global__ void k_softT(const float* __restrict__ S, float* __restrict__ ST) {
    int b = blockIdx.x >> 1;
    int c0 = (blockIdx.x & 1) * 256;
    int tid = threadIdx.x;  // 256
    int c = c0 + tid;
    bool act = c < N;
    const float* p = S + (size_t)b * N * N + c;
    float m = -1e30f, s = 0.f;
    if (act) {
        for (int r = 0; r < N; r++) m = fmaxf(m, p[(size_t)r * N]);
        for (int r = 0; r < N; r++) s += expf(p[(size_t)r * N] - m);
    }
    float inv = act ? 1.f / s : 0.f;
    __shared__ float tile[32][257];
    float* STb = ST + (size_t)b * N * N;
    for (int r0 = 0; r0 < N; r0 += 32) {
        int rmax = min(32, N - r0);
        if (act)
            for (int rr = 0; rr < rmax; rr++)
                tile[rr][tid] = expf(p[(size_t)(r0 + rr) * N] - m) * inv;
        __syncthreads();
        for (int it = 0; it < 32; it++) {
            int cl = 8 * it + (tid >> 5);
            int cc = c0 + cl;
            int r = r0 + (tid & 31);
            if (cc < N && (tid & 31) < rmax) STb[(size_t)cc * N + r] = tile[tid & 31][cl];
        }
        __syncthreads();
    }
}

// ---------------- chebyshev graph conv + Theta + relu -> sg (in d_out) ----------------

constexpr int JT = 4;
constexpr int NJB = (N + JT - 1) / JT;  // 77
constexpr int GGRID = B * NJB;          // 4928 = 8*616
constexpr int IP = 320;                 // padded K dim (307 -> 320)

// xI: fragment-linear bf16 x. xI[((b*48+et)*10+ks)*64 + lane]*8 holds
// x[b][i=ks*32+(lane>>4)*8+r][e=et*16+(lane&15)] for r=0..7.
constexpr long XI_TOT = (long)B * 48 * 10 * 64;

__global__ void k_xI(const float* __restrict__ x, unsigned short* __restrict__ xI) {
    long idx = (long)blockIdx.x * 256 + threadIdx.x;
    if (idx >= XI_TOT) return;
    int lane = (int)(idx & 63);
    int ks = (int)((idx >> 6) % 10);
    int et = (int)((idx / 640) % 48);
    int b = (int)(idx / 30720);
    int col = lane & 15, kg = lane >> 4;
    int i0 = ks * 32 + kg * 8;
    int e = et * 16 + col;
    const float* xp = x + (size_t)b * N * FT + e;
    s16x8 out;
#pragma unroll
    for (int r = 0; r < 8; r++) {
        int i = i0 + r;
        out[r] = (i < N) ? (short)f2bf(xp[(size_t)i * FT]) : (short)0;
    }
    *(s16x8*)(xI + (size_t)idx * 8) = out;
}

// WqT[b][jb][q=k*4+jj][i320] bf16 = cheb[k][i][j]*S[b][i][j], j = jb*4+jj
// v2: index space (b,jb,jj,i) with k-loop inside -> ST read ONCE per (j,i)
// (was 3x = 72MB), 3 coalesced bf16 store streams. Output bytes identical to v1.
__global__ void k_Wq16(const float* __restrict__ chebT, const float* __restrict__ ST,
                       unsigned short* __restrict__ Wq) {
    long idx = (long)blockIdx.x * 256 + threadIdx.x;
    long tot = (long)B * NJB * 4 * IP;
    if (idx >= tot) return;
    int i = (int)(idx % IP);
    int jj = (int)((idx / IP) % 4);
    int jb = (int)((idx / (4L * IP)) % NJB);
    int b = (int)(idx / (4L * IP * NJB));
    int j = jb * 4 + jj;
    float sv = 0.f;
    if (i < N && j < N) sv = ST[((size_t)b * N + j) * N + i];
    unsigned short* wq = Wq + ((size_t)(b * NJB + jb) * 12 + jj) * IP + i;
#pragma unroll
    for (int k = 0; k < K; k++) {
        float w = 0.f;
        if (i < N && j < N) w = chebT[((size_t)k * N + j) * N + i] * sv;
        wq[(size_t)k * 4 * IP] = f2bf(w);
    }
}

// MFMA stage-1 (round-8/10 proven version, 233us): 256 threads, 4 waves x 12
// e-tiles, depth-1 software pipeline at half-iteration granularity.
// launch_bounds(256,3): VGPR 84, zero spill. DO NOT raise the min-waves bound
// ((512,6) spilled 620MB, r9); ks-granular dbuf was neutral (r11).
__global__ __launch_bounds__(256, 3) void k_gcnz_m(const unsigned short* __restrict__ xI,
                                                   const unsigned short* __restrict__ WqT,
                                                   const float* __restrict__ ThT,
                                                   float* __restrict__ sg) {
    int blk0 = blockIdx.x;
    int blk = (blk0 & 7) * (GGRID / 8) + (blk0 >> 3);  // XCD swizzle (bijective: 4928=8*616)
    int b = blk / NJB;
    int jb = blk % NJB;
    int j0 = jb * JT;
    int tid = threadIdx.x;  // 256
    int w = tid >> 6;
    int lane = tid & 63;
    int col = lane & 15;  // A-row (q) / B-col (e within 16-tile)
    int kg = lane >> 4;

    __shared__ float zlf[3 * 3080];  // 3 k-planes of 3072 + 8 pad

    vf4 acc[12];
#pragma unroll
    for (int mt = 0; mt < 12; mt++) acc[mt] = (vf4){0.f, 0.f, 0.f, 0.f};

    const unsigned short* xb =
        xI + ((size_t)(b * 48 + w * 12) * 10) * 512 + (size_t)lane * 8;
    const unsigned short* wb =
        WqT + ((size_t)(b * NJB + jb) * 12 + (col < 12 ? col : 11)) * IP + kg * 8;

    s16x8 cx[6], nx[6], cw, nw;
    auto ldx = [&](s16x8* d, int h, int ks) {
#pragma unroll
        for (int m = 0; m < 6; m++)
            d[m] = *(const s16x8*)(xb + (size_t)((h * 6 + m) * 10 + ks) * 512);
    };

    cw = *(const s16x8*)(wb);
    ldx(cx, 0, 0);
#pragma unroll
    for (int step = 0; step < 20; step++) {
        int ks = step >> 1, h = step & 1;
        if (step < 19) {
            int ns = step + 1;
            int nks = ns >> 1, nh = ns & 1;
            nw = (nh == 0) ? *(const s16x8*)(wb + nks * 32) : cw;
            ldx(nx, nh, nks);
        }
#pragma unroll
        for (int m = 0; m < 6; m++)
            acc[h * 6 + m] =
                __builtin_amdgcn_mfma_f32_16x16x32_bf16(cw, cx[m], acc[h * 6 + m], 0, 0, 0);
        if (step < 19) {
            cw = nw;
#pragma unroll
            for (int m = 0; m < 6; m++) cx[m] = nx[m];
        }
        (void)ks;
    }

    if (kg < 3) {
        // acc[mt]: q = kg*4 + 0..3 for e = w*192 + mt*16 + col -> one b128 per mt
#pragma unroll
        for (int mt = 0; mt < 12; mt++) {
            int e = w * 192 + mt * 16 + col;  // = f*T + t
            *(vf4*)(zlf + kg * 3080 + e * 4) = acc[mt];
        }
    }
    __syncthreads();

    // Theta contraction, c-blocked (192 active threads)
    if (tid < 192) {
        int t = tid % T;
        int c0 = (tid / T) * 4;
        float s[4][4];
#pragma unroll
        for (int cc = 0; cc < 4; cc++)
#pragma unroll
            for (int jj = 0; jj < 4; jj++) s[cc][jj] = 0.f;

#pragma unroll
        for (int k = 0; k < K; k++) {
            const vf4* zpk = (const vf4*)(zlf + k * 3080 + t * 4);
            const vf4* tp0 = (const vf4*)(ThT + ((size_t)k * C + c0 + 0) * F);
            const vf4* tp1 = (const vf4*)(ThT + ((size_t)k * C + c0 + 1) * F);
            const vf4* tp2 = (const vf4*)(ThT + ((size_t)k * C + c0 + 2) * F);
            const vf4* tp3 = (const vf4*)(ThT + ((size_t)k * C + c0 + 3) * F);
#pragma unroll 4
            for (int fq = 0; fq < F / 4; fq++) {
                vf4 z0 = zpk[(4 * fq + 0) * 12];
                vf4 z1 = zpk[(4 * fq + 1) * 12];
                vf4 z2 = zpk[(4 * fq + 2) * 12];
                vf4 z3 = zpk[(4 * fq + 3) * 12];
                vf4 th[4];
                th[0] = tp0[fq];
                th[1] = tp1[fq];
                th[2] = tp2[fq];
                th[3] = tp3[fq];
#pragma unroll
                for (int cc = 0; cc < 4; cc++) {
#pragma unroll
                    for (int jj = 0; jj < 4; jj++)
                        s[cc][jj] += th[cc][0] * z0[jj] + th[cc][1] * z1[jj] +
                                     th[cc][2] * z2[jj] + th[cc][3] * z3[jj];
                }
            }
        }
#pragma unroll
        for (int jj = 0; jj < 4; jj++) {
            int j = j0 + jj;
            if (j < N) {
                float* op = sg + ((size_t)b * N + j) * FT + (size_t)c0 * T + t;
                op[0 * T] = fmaxf(s[0][jj], 0.f);
                op[1 * T] = fmaxf(s[1][jj], 0.f);
                op[2 * T] = fmaxf(s[2][jj], 0.f);
                op[3 * T] = fmaxf(s[3][jj], 0.f);
            }
        }
    }
}

// ---------------- fallback fp32 path (round-6, known-good) ----------------

__global__ void k_Wp(const float* __restrict__ cheb, const float* __restrict__ S,
                     float* __restrict__ Wp) {
    long idx = (long)blockIdx.x * 256 + threadIdx.x;
    long tot = (long)B * NJB * N * 12;
    if (idx >= tot) return;
    int q = (int)(idx % 12);
    int i = (int)((idx / 12) % N);
    int jb = (int)((idx / (12L * N)) % NJB);
    int b = (int)(idx / (12L * N * NJB));
    int k = q >> 2, jj = q & 3;
    int j = jb * 4 + jj;
    float w = 0.f;
    if (j < N) w = cheb[((size_t)k * N + i) * N + j] * S[((size_t)b * N + i) * N + j];
    Wp[idx] = w;
}

__global__ __launch_bounds__(256, 4) void k_gcnz_p(const float* __restrict__ x,
                                                   const float* __restrict__ Wp,
                                                   const float* __restrict__ ThT,
                                                   float* __restrict__ sg) {
    int blk0 = blockIdx.x;
    int blk = (blk0 & 7) * (GGRID / 8) + (blk0 >> 3);
    int b = blk / NJB;
    int jb = blk % NJB;
    int j0 = jb * JT;
    int tid = threadIdx.x;

    __shared__ float zl[K][F][T][JT];

    float acc[K * JT][3];
#pragma unroll
    for (int m = 0; m < K * JT; m++)
#pragma unroll
        for (int r = 0; r < 3; r++) acc[m][r] = 0.f;

    const float* xp = x + (size_t)b * N * FT + 3 * tid;
    const float* wb = Wp + ((size_t)b * NJB + jb) * N * 12;

    float w0[12], w1[12], w2[12];
    float x0[3], x1[3], x2[3];

    auto LD = [&](float* wreg, float* xreg, int i) {
        const vf4* p = (const vf4*)(wb + (size_t)i * 12);
        vf4 a = p[0], b4 = p[1], c4 = p[2];
#pragma unroll
        for (int q = 0; q < 4; q++) {
            wreg[q] = a[q];
            wreg[4 + q] = b4[q];
            wreg[8 + q] = c4[q];
        }
        const float* xq = xp + (size_t)i * FT;
        xreg[0] = xq[0];
        xreg[1] = xq[1];
        xreg[2] = xq[2];
    };
    auto FMA = [&](const float* wreg, const float* xreg) {
#pragma unroll
        for (int m = 0; m < K * JT; m++) {
            acc[m][0] += wreg[m] * xreg[0];
            acc[m][1] += wreg[m] * xreg[1];
            acc[m][2] += wreg[m] * xreg[2];
        }
    };

    LD(w0, x0, 0);
    LD(w1, x1, 1);
    LD(w2, x2, 2);
    int i = 0;
    for (; i + 5 < N; i += 3) {
        float a0[12], a1[12], a2[12], y0[3], y1[3], y2[3];
        LD(a0, y0, i + 3);
        LD(a1, y1, i + 4);
        LD(a2, y2, i + 5);
        FMA(w0, x0);
        FMA(w1, x1);
        FMA(w2, x2);
#pragma unroll
        for (int m = 0; m < 12; m++) {
            w0[m] = a0[m];
            w1[m] = a1[m];
            w2[m] = a2[m];
        }
#pragma unroll
        for (int r = 0; r < 3; r++) {
            x0[r] = y0[r];
            x1[r] = y1[r];
            x2[r] = y2[r];
        }
    }
    FMA(w0, x0);
    FMA(w1, x1);
    FMA(w2, x2);
    for (i += 3; i < N; i++) {
        LD(w0, x0, i);
        FMA(w0, x0);
    }

#pragma unroll
    for (int r = 0; r < 3; r++) {
        int e = 3 * tid + r;
        int f = e / T, t = e % T;
#pragma unroll
        for (int m = 0; m < K * JT; m++) zl[m >> 2][f][t][m & 3] = acc[m][r];
    }
    __syncthreads();

    if (tid < 192) {
        int t = tid % T;
        int c0 = (tid / T) * 4;
        float s[4][4];
#pragma unroll
        for (int cc = 0; cc < 4; cc++)
#pragma unroll
            for (int jj = 0; jj < 4; jj++) s[cc][jj] = 0.f;

#pragma unroll
        for (int k = 0; k < K; k++) {
            const vf4* zpk = (const vf4*)&zl[k][0][t][0];
            const vf4* tp0 = (const vf4*)(ThT + ((size_t)k * C + c0 + 0) * F);
            const vf4* tp1 = (const vf4*)(ThT + ((size_t)k * C + c0 + 1) * F);
            const vf4* tp2 = (const vf4*)(ThT + ((size_t)k * C + c0 + 2) * F);
            const vf4* tp3 = (const vf4*)(ThT + ((size_t)k * C + c0 + 3) * F);
#pragma unroll 4
            for (int fq = 0; fq < F / 4; fq++) {
                vf4 z0 = zpk[(4 * fq + 0) * 12];
                vf4 z1 = zpk[(4 * fq + 1) * 12];
                vf4 z2 = zpk[(4 * fq + 2) * 12];
                vf4 z3 = zpk[(4 * fq + 3) * 12];
                vf4 th[4];
                th[0] = tp0[fq];
                th[1] = tp1[fq];
                th[2] = tp2[fq];
                th[3] = tp3[fq];
#pragma unroll
                for (int cc = 0; cc < 4; cc++) {
#pragma unroll
                    for (int jj = 0; jj < 4; jj++)
                        s[cc][jj] += th[cc][0] * z0[jj] + th[cc][1] * z1[jj] +
                                     th[cc][2] * z2[jj] + th[cc][3] * z3[jj];
                }
            }
        }
#pragma unroll
        for (int jj = 0; jj < 4; jj++) {
            int j = j0 + jj;
            if (j < N) {
                float* op = sg + ((size_t)b * N + j) * FT + (size_t)c0 * T + t;
                op[0 * T] = fmaxf(s[0][jj], 0.f);
                op[1 * T] = fmaxf(s[1][jj], 0.f);
                op[2 * T] = fmaxf(s[2][jj], 0.f);
                op[3 * T] = fmaxf(s[3][jj], 0.f);
            }
        }
    }
}

// ---------------- tconv + rconv + relu + LayerNorm (in-place on d_out) ----------------

constexpr int RB = 4;
constexpr int PF = 68;

__global__ void k_rest(const float* __restrict__ x, const float* __restrict__ twT,
                       const float* __restrict__ tb, const float* __restrict__ rw,
                       const float* __restrict__ rb, const float* __restrict__ gamma,
                       const float* __restrict__ beta, float* __restrict__ io) {
    int blk = blockIdx.x;
    size_t bn0 = (size_t)blk * RB;
    int tid = threadIdx.x;  // 192

    __shared__ float xt[RB][T][PF];
    __shared__ float sgt[RB][T + 2][PF];
    __shared__ float red0[RB][T][17];
    __shared__ float red1[RB][T][17];
    __shared__ float mus[RB][T], rstds[RB][T];

    for (int l = tid; l < RB * PF; l += 192) {
        int rr = l / PF, c = l % PF;
        sgt[rr][0][c] = 0.f;
        sgt[rr][T + 1][c] = 0.f;
    }
    for (int l = tid; l < RB * FT; l += 192) {
        int rr = l / FT, rem = l % FT;
        int f = rem / T, t = rem % T;
        xt[rr][t][f] = x[(bn0 + rr) * FT + rem];
        sgt[rr][t + 1][f] = io[(bn0 + rr) * FT + rem];
    }
    __syncthreads();

    int t = tid % T;
    int cg = tid / T;
    int ct0 = cg * 4;

    float acc[RB][4];
#pragma unroll
    for (int rr = 0; rr < RB; rr++)
#pragma unroll
        for (int q = 0; q < 4; q++) acc[rr][q] = rb[ct0 + q] + tb[ct0 + q];

    {
        const vf4* w0 = (const vf4*)(rw + (size_t)(ct0 + 0) * F);
        const vf4* w1 = (const vf4*)(rw + (size_t)(ct0 + 1) * F);
        const vf4* w2 = (const vf4*)(rw + (size_t)(ct0 + 2) * F);
        const vf4* w3 = (const vf4*)(rw + (size_t)(ct0 + 3) * F);
#pragma unroll 4
        for (int fq = 0; fq < F / 4; fq++) {
            vf4 a = w0[fq], b4 = w1[fq], c4 = w2[fq], d4 = w3[fq];
#pragma unroll
            for (int rr = 0; rr < RB; rr++) {
                vf4 v = *(const vf4*)(&xt[rr][t][fq * 4]);
                acc[rr][0] += a[0] * v[0] + a[1] * v[1] + a[2] * v[2] + a[3] * v[3];
                acc[rr][1] += b4[0] * v[0] + b4[1] * v[1] + b4[2] * v[2] + b4[3] * v[3];
                acc[rr][2] += c4[0] * v[0] + c4[1] * v[1] + c4[2] * v[2] + c4[3] * v[3];
                acc[rr][3] += d4[0] * v[0] + d4[1] * v[1] + d4[2] * v[2] + d4[3] * v[3];
            }
        }
    }
#pragma unroll
    for (int dt = 0; dt < 3; dt++) {
        const vf4* w0 = (const vf4*)(twT + ((size_t)dt * CT + ct0 + 0) * C);
        const vf4* w1 = (const vf4*)(twT + ((size_t)dt * CT + ct0 + 1) * C);
        const vf4* w2 = (const vf4*)(twT + ((size_t)dt * CT + ct0 + 2) * C);
        const vf4* w3 = (const vf4*)(twT + ((size_t)dt * CT + ct0 + 3) * C);
#pragma unroll 4
        for (int fq = 0; fq < C / 4; fq++) {
            vf4 a = w0[fq], b4 = w1[fq], c4 = w2[fq], d4 = w3[fq];
#pragma unroll
            for (int rr = 0; rr < RB; rr++) {
                vf4 v = *(const vf4*)(&sgt[rr][t + dt][fq * 4]);
                acc[rr][0] += a[0] * v[0] + a[1] * v[1] + a[2] * v[2] + a[3] * v[3];
                acc[rr][1] += b4[0] * v[0] + b4[1] * v[1] + b4[2] * v[2] + b4[3] * v[3];
                acc[rr][2] += c4[0] * v[0] + c4[1] * v[1] + c4[2] * v[2] + c4[3] * v[3];
                acc[rr][3] += d4[0] * v[0] + d4[1] * v[1] + d4[2] * v[2] + d4[3] * v[3];
            }
        }
    }

#pragma unroll
    for (int rr = 0; rr < RB; rr++) {
        float ps = 0.f;
#pragma unroll
        for (int q = 0; q < 4; q++) {
            float h = fmaxf(acc[rr][q], 0.f);
            acc[rr][q] = h;
            ps += h;
        }
        red0[rr][t][cg] = ps;
    }
    __syncthreads();
    if (tid < RB * T) {
        int rr = tid / T, tt = tid % T;
        float m = 0.f;
#pragma unroll 4
        for (int g = 0; g < 16; g++) m += red0[rr][tt][g];
        mus[rr][tt] = m * (1.f / CT);
    }
    __syncthreads();
#pragma unroll
    for (int rr = 0; rr < RB; rr++) {
        float m = mus[rr][t];
        float pv = 0.f;
#pragma unroll
        for (int q = 0; q < 4; q++) {
            float d = acc[rr][q] - m;
            pv += d * d;
        }
        red1[rr][t][cg] = pv;
    }
    __syncthreads();
    if (tid < RB * T) {
        int rr = tid / T, tt = tid % T;
        float v = 0.f;
#pragma unroll 4
        for (int g = 0; g < 16; g++) v += red1[rr][tt][g];
        rstds[rr][tt] = rsqrtf(v * (1.f / CT) + LN_EPS);
    }
    __syncthreads();
#pragma unroll
    for (int rr = 0; rr < RB; rr++) {
        float m = mus[rr][t], rs = rstds[rr][t];
        float* iop = io + (bn0 + rr) * FT;
#pragma unroll
        for (int q = 0; q < 4; q++) {
            int ct = ct0 + q;
            iop[ct * T + t] = (acc[rr][q] - m) * rs * gamma[ct] + beta[ct];
        }
    }
}

// ---------------- launch ----------------

extern "C" void kernel_launch(void* const* d_in, const int* in_sizes, int n_in,
                              void* d_out, int out_size, void* d_ws, size_t ws_size,
                              hipStream_t stream) {
    const float* x     = (const float*)d_in[0];
    const float* W1    = (const float*)d_in[1];
    const float* W2    = (const float*)d_in[2];
    const float* W3    = (const float*)d_in[3];
    const float* b_s   = (const float*)d_in[4];
    const float* V_s   = (const float*)d_in[5];
    const float* U1    = (const float*)d_in[6];
    const float* U2    = (const float*)d_in[7];
    const float* U3    = (const float*)d_in[8];
    const float* b_e   = (const float*)d_in[9];
    const float* V_e   = (const float*)d_in[10];
    const float* cheb  = (const float*)d_in[11];
    const float* Theta = (const float*)d_in[12];
    const float* tw    = (const float*)d_in[13];
    const float* tb    = (const float*)d_in[14];
    const float* rw    = (const float*)d_in[15];
    const float* rb    = (const float*)d_in[16];
    const float* gam   = (const float*)d_in[17];
    const float* bet   = (const float*)d_in[18];
    float* out = (float*)d_out;

    float* ws = (float*)d_ws;
    size_t off = 0;
    auto alloc = [&](size_t n) { float* p = ws + off; off += n; return p; };
    // persistent
    float* VsT = alloc((size_t)N * N);
    float* twT = alloc((size_t)CT * C * 3);
    float* ThT = alloc((size_t)K * F * C);
    size_t base_end = off;
    // attention transients (dead before k_Wq16)
    float* lhs1_e = alloc((size_t)B * T * F);
    float* lhs_e  = alloc((size_t)B * T * N);
    float* rhs_e  = alloc((size_t)B * N * T);
    float* Ebuf   = alloc((size_t)B * T * T);
    float* EW1    = alloc((size_t)B * T);
    float* xw3    = alloc((size_t)B * N * T);
    float* lhs_s  = alloc((size_t)B * N * T);
    float* rhs_s  = alloc((size_t)B * T * N);
    float* Sb     = alloc((size_t)B * N * N);
    size_t poolA_end = off;

    // MFMA-path buffers: WqT overlays transients (written after they're dead)
    size_t wq_fl = (size_t)B * NJB * 12 * IP / 2;  // ushorts/2
    unsigned short* WqT = (unsigned short*)(ws + base_end);
    size_t off2 = base_end + wq_fl;
    if (off2 < poolA_end) off2 = poolA_end;
    float* chebT = ws + off2; off2 += (size_t)K * N * N;
    float* SbT = ws + off2; off2 += (size_t)B * N * N;
    unsigned short* xI = (unsigned short*)(ws + off2);
    off2 += (size_t)XI_TOT * 8 / 2;
    bool useM = ws_size >= off2 * sizeof(float);

    // fallback fp32 Wp (round-6 layout)
    size_t wp_off = (poolA_end + 3) & ~(size_t)3;
    float* Wp = ws + wp_off;
    bool useWp = !useM && ws_size >= (wp_off + (size_t)B * NJB * N * 12) * sizeof(float);

    auto g = [](long n) { return dim3((unsigned)((n + 255) / 256)); };

    // prep (chebT section only needed when useM)
    k_prep<<<g(useM ? (long)PREP_TOT2 : (long)PREP_TOT), 256, 0, stream>>>(
        V_s, tw, Theta, cheb, VsT, twT, ThT, chebT);
    if (useM) k_xI<<<g(XI_TOT), 256, 0, stream>>>(x, xI);

    // temporal attention
    k_lhs1_e<<<dim3(B * 3), 256, 0, stream>>>(x, U1, lhs1_e);
    k_xdots<<<g((long)B * N * T), 256, 0, stream>>>(x, U3, W3, rhs_e, xw3);
    k_lhs_e<<<g((long)B * T * N), 256, 0, stream>>>(lhs1_e, U2, lhs_e);
    k_tatt<<<B, 256, 0, stream>>>(lhs_e, rhs_e, b_e, V_e, W1, Ebuf, EW1);

    // spatial attention
    k_lhs_sf<<<dim3((B * N) / 4), 256, 0, stream>>>(x, EW1, W2, lhs_s);
    k_rhs_s2<<<g((long)B * T * N), 256, 0, stream>>>(xw3, Ebuf, rhs_s);
    k_sigS<<<B * NAB, 256, 0, stream>>>(lhs_s, rhs_s, b_s, VsT, Sb);

    // graph conv + Theta + relu -> sg staged in d_out
    if (useM) {
        k_softT<<<dim3(B * 2), 256, 0, stream>>>(Sb, SbT);
        k_Wq16<<<g((long)B * NJB * 4 * IP), 256, 0, stream>>>(chebT, SbT, WqT);
        k_gcnz_m<<<GGRID, 256, 0, stream>>>(xI, WqT, ThT, out);
    } else if (useWp) {
        k_softmax_S<<<g((long)B * N), 256, 0, stream>>>(Sb);
        k_Wp<<<g((long)B * NJB * N * 12), 256, 0, stream>>>(cheb, Sb, Wp);
        k_gcnz_p<<<GGRID, 256, 0, stream>>>(x, Wp, ThT, out);
    }

    // tconv + rconv + relu + LN, in-place on d_out
    k_rest<<<(B * N) / RB, 192, 0, stream>>>(x, twT, tb, rw, rb, gam, bet, out);
}